// Round 5
// baseline (220.619 us; speedup 1.0000x reference)
//
#include <hip/hip_runtime.h>
#include <hip/hip_bf16.h>

// ChannelDense: y[b,n,o] = tanh( sum_i x[b,n,i]*W[c[n],o,i] + bias[c[n],o] ) + x[b,n,o]
// B=128, N=2048, IN=OUT=256, 64 channels.
//
// R5 structure: channel-persistent workgroups.
//  k0 sort: counting-sort points by channel -> perm + start[65]; also writes the
//     channels passthrough output.
//  k1 wconv: W f32 -> bf16 linear image in d_ws (halves W bytes, enables b128 frag loads).
//  k2 main: 256 wgs = 64 channels x 4 point-chunks, 512 thr (8 waves).
//     Each wave holds W[c] for its 32-wide o-strip IN REGISTERS (wreg[2][8] bf16x8 =
//     64 VGPR) -- loaded once per wg. Loop over the chunk's points: A = x[:,n,:] bf16
//     in LDS double-buffer (2 x 64KB; slab layout [kt][128r][64B], swizzle ^((r&7)<<4)),
//     T14 async split staging (loads for p+1 issued before/inside p's compute, ds_writes
//     after), ONE barrier per point. Epilogue: bias+tanh+residual(from LDS A), float4
//     stores. No W staging in the loop at all.

#define N_SZ 2048

typedef __attribute__((ext_vector_type(8))) __bf16 bf16x8;
typedef __attribute__((ext_vector_type(4))) float  f32x4;

__device__ __forceinline__ unsigned f2bf1(float f) {
    union { float f; unsigned u; } v; v.f = f;
    return (v.u + 0x7fffu + ((v.u >> 16) & 1u)) >> 16;   // RNE
}
__device__ __forceinline__ int pack2(float lo, float hi) {
    return (int)(f2bf1(lo) | (f2bf1(hi) << 16));
}
__device__ __forceinline__ float bf2f(unsigned u16) {
    union { unsigned u; float f; } v; v.u = u16 << 16;
    return v.f;
}
__device__ __forceinline__ float tanh_fast(float s) {
    float a = fabsf(s);
    float t = __expf(-2.0f * a);
    float r = (1.0f - t) * __builtin_amdgcn_rcpf(1.0f + t);
    return __builtin_copysignf(r, s);
}

// ---- k0: counting sort + start[] + channels passthrough ----
__global__ __launch_bounds__(1024) void sort_kernel(const int* __restrict__ channels,
                                                    int* __restrict__ perm,
                                                    int* __restrict__ start,
                                                    float* __restrict__ out_ch) {
    __shared__ int cnt[64], off[64];
    const int t = threadIdx.x;
    if (t < 64) cnt[t] = 0;
    __syncthreads();
    const int n0 = t, n1 = t + 1024;
    const int c0 = channels[n0], c1 = channels[n1];
    atomicAdd(&cnt[c0], 1);
    atomicAdd(&cnt[c1], 1);
    out_ch[n0] = (float)c0;
    out_ch[n1] = (float)c1;
    __syncthreads();
    if (t == 0) {
        int s = 0;
        for (int i = 0; i < 64; ++i) { start[i] = s; off[i] = s; s += cnt[i]; }
        start[64] = s;
    }
    __syncthreads();
    int p0 = atomicAdd(&off[c0], 1); perm[p0] = n0;
    int p1 = atomicAdd(&off[c1], 1); perm[p1] = n1;
}

// ---- k1: W f32 -> bf16 linear image ----
__global__ __launch_bounds__(256) void wconv_kernel(const float* __restrict__ w,
                                                    unsigned short* __restrict__ wsW) {
    const size_t t = (size_t)blockIdx.x * 256 + threadIdx.x;   // 524288 chunks of 8
    const float* src = w + t * 8;
    float4 f0 = *(const float4*)(src);
    float4 f1 = *(const float4*)(src + 4);
    int4 p;
    p.x = pack2(f0.x, f0.y); p.y = pack2(f0.z, f0.w);
    p.z = pack2(f1.x, f1.y); p.w = pack2(f1.z, f1.w);
    *(int4*)(wsW + t * 8) = p;
}

// ---- k2: main ----
__global__ __launch_bounds__(512, 2) void channel_dense_kernel(
    const float* __restrict__ x, const int* __restrict__ perm,
    const int* __restrict__ start, const unsigned short* __restrict__ wsW,
    const float* __restrict__ bias, float* __restrict__ y)
{
    __shared__ __align__(16) unsigned char sA[2][65536];   // [kt=8][r=128][64B] each

    const int c = blockIdx.x >> 2, chunk = blockIdx.x & 3;
    const int s0 = start[c], cnt = start[c + 1] - s0;
    const int p_begin = s0 + ((cnt * chunk) >> 2);
    const int p_end   = s0 + ((cnt * (chunk + 1)) >> 2);
    if (p_begin >= p_end) return;                          // wg-uniform

    const int tid  = threadIdx.x;
    const int lane = tid & 63, wv = tid >> 6;
    const int lr   = lane & 15, lg4 = lane >> 4;

    // --- W fragments in registers (o-strip = wv*32 .. +32) ---
    bf16x8 wreg[2][8];
    {
        const unsigned short* wb = wsW + ((size_t)c << 16);
        #pragma unroll
        for (int mo = 0; mo < 2; ++mo) {
            const unsigned short* wr_ = wb + (wv * 32 + mo * 16 + lr) * 256 + lg4 * 8;
            #pragma unroll
            for (int kt = 0; kt < 8; ++kt)
                wreg[mo][kt] = *(const bf16x8*)(wr_ + kt * 32);
        }
    }
    float4 bv[2];
    bv[0] = *(const float4*)(bias + c * 256 + wv * 32 + lg4 * 4);
    bv[1] = *(const float4*)(bias + c * 256 + wv * 32 + 16 + lg4 * 4);

    // --- A staging: thread owns row r, 16B sub-column qt; 64 floats/point ---
    const int r  = tid >> 2;
    const int qt = tid & 3;
    const int wbyte = (r * 64 + qt * 16) ^ ((r & 7) << 4);
    float4 la[8];

    auto stage_load = [&](int n_, int h) {                 // 8 x float4, 128B/4-lane grp
        const float* xb = x + ((size_t)r * N_SZ + n_) * 256 + h * 128 + qt * 8;
        #pragma unroll
        for (int j = 0; j < 4; ++j) {
            la[2 * j]     = *(const float4*)(xb + j * 32);
            la[2 * j + 1] = *(const float4*)(xb + j * 32 + 4);
        }
    };
    auto stage_write = [&](int buf, int h) {               // 4 x ds_write_b128
        #pragma unroll
        for (int j = 0; j < 4; ++j) {
            int4 p;
            p.x = pack2(la[2*j].x,   la[2*j].y);   p.y = pack2(la[2*j].z,   la[2*j].w);
            p.z = pack2(la[2*j+1].x, la[2*j+1].y); p.w = pack2(la[2*j+1].z, la[2*j+1].w);
            *(int4*)(&sA[buf][(h * 4 + j) * 8192 + wbyte]) = p;
        }
    };

    int n_cur = perm[p_begin];
    int n_nxt = 0;

    // prologue: stage first point into buf 0
    stage_load(n_cur, 0); stage_write(0, 0);
    stage_load(n_cur, 1); stage_write(0, 1);
    __syncthreads();

    const int lanebyte = (lr * 64 + lg4 * 16) ^ ((lr & 7) << 4);

    for (int p = p_begin; p < p_end; ++p) {
        const int cur = (p - p_begin) & 1, nxt = cur ^ 1;
        const bool more = (p + 1 < p_end);
        if (more) { n_nxt = perm[p + 1]; stage_load(n_nxt, 0); }   // in flight over compute

        f32x4 acc[2][8] = {};
        #pragma unroll
        for (int kt = 0; kt < 8; ++kt) {
            bf16x8 xf[8];
            #pragma unroll
            for (int nb = 0; nb < 8; ++nb)
                xf[nb] = *(const bf16x8*)(&sA[cur][kt * 8192 + nb * 1024 + lanebyte]);
            #pragma unroll
            for (int nb = 0; nb < 8; ++nb) {
                acc[0][nb] = __builtin_amdgcn_mfma_f32_16x16x32_bf16(wreg[0][kt], xf[nb], acc[0][nb], 0, 0, 0);
                acc[1][nb] = __builtin_amdgcn_mfma_f32_16x16x32_bf16(wreg[1][kt], xf[nb], acc[1][nb], 0, 0, 0);
            }
        }

        if (more) { stage_write(nxt, 0); stage_load(n_nxt, 1); }  // h1 in flight over epilogue

        // epilogue: bias + tanh + residual(from LDS) + float4 stores
        #pragma unroll
        for (int mo = 0; mo < 2; ++mo) {
            const int o0 = wv * 32 + mo * 16 + lg4 * 4;
            #pragma unroll
            for (int nb = 0; nb < 8; ++nb) {
                const int b = nb * 16 + lr;
                uint2 rv = *(const uint2*)(&sA[cur][wv * 8192 +
                              ((b * 64 + mo * 32 + lg4 * 8) ^ ((lr & 7) << 4))]);
                float4 o;
                o.x = tanh_fast(acc[mo][nb][0] + bv[mo].x) + bf2f(rv.x & 0xffffu);
                o.y = tanh_fast(acc[mo][nb][1] + bv[mo].y) + bf2f(rv.x >> 16);
                o.z = tanh_fast(acc[mo][nb][2] + bv[mo].z) + bf2f(rv.y & 0xffffu);
                o.w = tanh_fast(acc[mo][nb][3] + bv[mo].w) + bf2f(rv.y >> 16);
                *(float4*)(y + ((size_t)b * N_SZ + n_cur) * 256 + o0) = o;
            }
        }

        if (more) stage_write(nxt, 1);
        __syncthreads();
        n_cur = n_nxt;
    }
}

extern "C" void kernel_launch(void* const* d_in, const int* in_sizes, int n_in,
                              void* d_out, int out_size, void* d_ws, size_t ws_size,
                              hipStream_t stream) {
    const float* x        = (const float*)d_in[0];
    const int*   channels = (const int*)d_in[1];
    const float* weight   = (const float*)d_in[2];
    const float* bias     = (const float*)d_in[3];
    float* y = (float*)d_out;

    unsigned short* wsW = (unsigned short*)d_ws;            // 8 MB bf16 W image
    int* perm  = (int*)((unsigned char*)d_ws + (64u << 17));// + 8KB perm
    int* start = perm + 2048;                               // + 260B start

    sort_kernel<<<dim3(1), dim3(1024), 0, stream>>>(
        channels, perm, start, y + (size_t)128 * N_SZ * 256);
    wconv_kernel<<<dim3(2048), dim3(256), 0, stream>>>(weight, wsW);
    channel_dense_kernel<<<dim3(256), dim3(512), 0, stream>>>(
        x, perm, start, wsW, bias, y);
}

// Round 6
// 190.679 us; speedup vs baseline: 1.1570x; 1.1570x over previous
//
#include <hip/hip_runtime.h>
#include <hip/hip_bf16.h>

// ChannelDense: y[b,n,o] = tanh( sum_i x[b,n,i]*W[c[n],o,i] + bias[c[n],o] ) + x[b,n,o]
// B=128, N=2048, IN=OUT=256, 64 channels.
//
// R6: occupancy-first, barrier-free main loop.
//  k0 sort: counting-sort by channel; perm packs (c<<16)|n; channels passthrough.
//  k1 wconv: W f32 -> bf16 linear image [c][o][k] in d_ws.
//  k2 main: grid 4096 = (sorted point) x (batch half), XCD-chunked. wg 512 thr =
//    8 waves, each wave owns a 32-wide o-strip. W fragments are loaded DIRECTLY
//    from the bf16 global image per kt (L2-hot via channel-sorted scheduling) --
//    no W registers held, no W LDS, no in-loop barriers. LDS = one 32KB x-tile
//    (64 rows x 256 k bf16, slab layout [kt][r][64B], swizzle ^((r&7)<<4)),
//    staged once with native-cast f32->bf16, ONE barrier, then 64 MFMA + epilogue
//    (bias + tanh + bf16 residual from LDS + float4 stores).
//  Budget: VGPR <=128 (launch_bounds 512,4) -> 16 waves/CU; LDS 32KB -> 2 wg/CU.

#define N_SZ 2048

typedef __attribute__((ext_vector_type(8))) __bf16 bf16x8;
typedef __attribute__((ext_vector_type(4))) float  f32x4;

__device__ __forceinline__ float bf2f(unsigned u16) {
    union { unsigned u; float f; } v; v.u = u16 << 16;
    return v.f;
}
__device__ __forceinline__ float tanh_fast(float s) {
    float a = fabsf(s);
    float t = __expf(-2.0f * a);
    float r = (1.0f - t) * __builtin_amdgcn_rcpf(1.0f + t);
    return __builtin_copysignf(r, s);
}
// 8 f32 -> bf16x8 via native casts (compiler emits v_cvt_pk_bf16_f32 pairs)
__device__ __forceinline__ bf16x8 cvt8(float4 a, float4 b) {
    bf16x8 v;
    v[0] = (__bf16)a.x; v[1] = (__bf16)a.y; v[2] = (__bf16)a.z; v[3] = (__bf16)a.w;
    v[4] = (__bf16)b.x; v[5] = (__bf16)b.y; v[6] = (__bf16)b.z; v[7] = (__bf16)b.w;
    return v;
}

// ---- k0: counting sort; perm[p] = (c<<16)|n; channels passthrough ----
__global__ __launch_bounds__(1024) void sort_kernel(const int* __restrict__ channels,
                                                    int* __restrict__ perm,
                                                    float* __restrict__ out_ch) {
    __shared__ int cnt[64], off[64];
    const int t = threadIdx.x;
    if (t < 64) cnt[t] = 0;
    __syncthreads();
    const int n0 = t, n1 = t + 1024;
    const int c0 = channels[n0], c1 = channels[n1];
    atomicAdd(&cnt[c0], 1);
    atomicAdd(&cnt[c1], 1);
    out_ch[n0] = (float)c0;
    out_ch[n1] = (float)c1;
    __syncthreads();
    if (t == 0) { int s = 0; for (int i = 0; i < 64; ++i) { off[i] = s; s += cnt[i]; } }
    __syncthreads();
    int p0 = atomicAdd(&off[c0], 1); perm[p0] = n0 | (c0 << 16);
    int p1 = atomicAdd(&off[c1], 1); perm[p1] = n1 | (c1 << 16);
}

// ---- k1: W f32 -> bf16 linear image ----
__global__ __launch_bounds__(256) void wconv_kernel(const float* __restrict__ w,
                                                    unsigned short* __restrict__ wsW) {
    const size_t t = (size_t)blockIdx.x * 256 + threadIdx.x;   // 524288 chunks of 8
    const float* src = w + t * 8;
    float4 f0 = *(const float4*)(src);
    float4 f1 = *(const float4*)(src + 4);
    bf16x8 v = cvt8(f0, f1);
    *(bf16x8*)(wsW + t * 8) = v;
}

// ---- k2: main ----
__global__ __launch_bounds__(512, 4) void channel_dense_kernel(
    const float* __restrict__ x, const int* __restrict__ perm,
    const unsigned short* __restrict__ wsW, const float* __restrict__ bias,
    float* __restrict__ y)
{
    __shared__ __align__(16) unsigned char sA[32768];   // [kt=8][r=64][64B]

    const int g    = blockIdx.x;
    const int lg   = (g & 7) * 512 + (g >> 3);          // XCD-chunked over sorted order
    const int pv   = perm[lg >> 1];
    const int n    = pv & 0xffff;
    const int c    = pv >> 16;
    const int half = lg & 1;
    const int tid  = threadIdx.x;

    // ---- A-stage: x[half*64 .. +64, n, :] -> bf16 LDS, staged once ----
    {
        const int r = tid >> 3;            // local row 0..63
        const int q = tid & 7;             // 32-float chunk = slab q
        const float* xr = x + ((size_t)(half * 64 + r) * N_SZ + n) * 256 + q * 32;
        float4 la[8];
        #pragma unroll
        for (int j = 0; j < 8; ++j) la[j] = *(const float4*)(xr + j * 4);
        const int swz = (r & 7) << 4;
        #pragma unroll
        for (int j = 0; j < 4; ++j) {
            bf16x8 v = cvt8(la[2 * j], la[2 * j + 1]);
            *(bf16x8*)(sA + q * 4096 + ((r * 64 + j * 16) ^ swz)) = v;
        }
    }
    __syncthreads();                       // the ONLY barrier

    const int lane = tid & 63, wv = tid >> 6;
    const int lr   = lane & 15, lg4 = lane >> 4;

    // W fragment base: lane (lr,lg4) of wave wv reads W[c][wv*32+mo*16+lr][kt*32+lg4*8 ..+8]
    const unsigned short* wl = wsW + (((size_t)c * 256 + wv * 32 + lr) << 8) + lg4 * 8;
    const int lanebyte = (lr * 64 + lg4 * 16) ^ ((lr & 7) << 4);

    f32x4 acc[2][4] = {};

    #pragma unroll
    for (int kt = 0; kt < 8; ++kt) {
        bf16x8 wf0 = *(const bf16x8*)(wl + kt * 32);            // o-strip rows 0..15
        bf16x8 wf1 = *(const bf16x8*)(wl + 16 * 256 + kt * 32); // rows 16..31
        bf16x8 xf[4];
        #pragma unroll
        for (int nb = 0; nb < 4; ++nb)
            xf[nb] = *(const bf16x8*)(sA + kt * 4096 + nb * 1024 + lanebyte);
        #pragma unroll
        for (int nb = 0; nb < 4; ++nb) {
            acc[0][nb] = __builtin_amdgcn_mfma_f32_16x16x32_bf16(wf0, xf[nb], acc[0][nb], 0, 0, 0);
            acc[1][nb] = __builtin_amdgcn_mfma_f32_16x16x32_bf16(wf1, xf[nb], acc[1][nb], 0, 0, 0);
        }
    }

    // ---- epilogue: bias + tanh + residual(LDS bf16) + float4 stores ----
    #pragma unroll
    for (int mo = 0; mo < 2; ++mo) {
        const int o0 = wv * 32 + mo * 16 + lg4 * 4;     // 4 consecutive o
        const float4 bv = *(const float4*)(bias + c * 256 + o0);
        #pragma unroll
        for (int nb = 0; nb < 4; ++nb) {
            const int rl = nb * 16 + lr;                // local b row
            const int b  = half * 64 + rl;
            // residual x[b][o0..o0+3]: slab = o0>>5 == wv (mo*16+lg4*4 < 32)
            const int rbyte = wv * 4096 + ((rl * 64 + mo * 32 + lg4 * 8) ^ ((rl & 7) << 4));
            uint2 rv = *(const uint2*)(sA + rbyte);
            float4 o;
            o.x = tanh_fast(acc[mo][nb][0] + bv.x) + bf2f(rv.x & 0xffffu);
            o.y = tanh_fast(acc[mo][nb][1] + bv.y) + bf2f(rv.x >> 16);
            o.z = tanh_fast(acc[mo][nb][2] + bv.z) + bf2f(rv.y & 0xffffu);
            o.w = tanh_fast(acc[mo][nb][3] + bv.w) + bf2f(rv.y >> 16);
            *(float4*)(y + ((size_t)b * N_SZ + n) * 256 + o0) = o;
        }
    }
}

extern "C" void kernel_launch(void* const* d_in, const int* in_sizes, int n_in,
                              void* d_out, int out_size, void* d_ws, size_t ws_size,
                              hipStream_t stream) {
    const float* x        = (const float*)d_in[0];
    const int*   channels = (const int*)d_in[1];
    const float* weight   = (const float*)d_in[2];
    const float* bias     = (const float*)d_in[3];
    float* y = (float*)d_out;

    unsigned short* wsW = (unsigned short*)d_ws;             // 8 MB bf16 W image
    int* perm = (int*)((unsigned char*)d_ws + (64u << 17));  // + 8KB perm

    sort_kernel<<<dim3(1), dim3(1024), 0, stream>>>(
        channels, perm, y + (size_t)128 * N_SZ * 256);
    wconv_kernel<<<dim3(2048), dim3(256), 0, stream>>>(weight, wsW);
    channel_dense_kernel<<<dim3(4096), dim3(512), 0, stream>>>(
        x, perm, wsW, bias, y);
}